// Round 1
// 413.232 us; speedup vs baseline: 1.0503x; 1.0503x over previous
//
#include <hip/hip_runtime.h>
#include <stdint.h>
#include <math.h>

typedef unsigned short u16;
typedef __attribute__((ext_vector_type(8))) __bf16 v8bf;
typedef v8bf __attribute__((may_alias)) v8bf_a;
typedef __attribute__((ext_vector_type(4))) float v4f;
typedef __attribute__((ext_vector_type(4))) u16 v4u16;
typedef v4u16 __attribute__((may_alias)) v4u16_a;
typedef __attribute__((ext_vector_type(8))) u16 v8u16;
typedef v8u16 __attribute__((may_alias)) v8u16_a;

__device__ __forceinline__ float bf2f(u16 u) {
    union { uint32_t i; float f; } c; c.i = ((uint32_t)u) << 16; return c.f;
}
__device__ __forceinline__ u16 f2bf(float f) {
    union { float f; uint32_t i; } c; c.f = f;
    return (u16)((c.i + 0x7FFFu + ((c.i >> 16) & 1u)) >> 16);
}
__device__ __forceinline__ void gl_lds16(const u16* g, u16* l) {
    __builtin_amdgcn_global_load_lds(
        (const __attribute__((address_space(1))) void*)g,
        (__attribute__((address_space(3))) void*)l, 16, 0, 0);
}

// ---------------------------------------------------------------------------
// fp32 -> bf16 conversion (inputs are fp32: proven by round-2/3 NaN bisect).
// ---------------------------------------------------------------------------
__global__ __launch_bounds__(256) void convert_bf16(
    const float* __restrict__ src, u16* __restrict__ dst, int n)
{
    const int stride = gridDim.x * blockDim.x;
    for (int i = blockIdx.x * blockDim.x + threadIdx.x; i * 8 < n; i += stride) {
        const int base = i * 8;
        v8u16 o;
#pragma unroll
        for (int j = 0; j < 8; j++) o[j] = f2bf(src[base + j]);
        *(v8u16_a*)(dst + base) = o;
    }
}

// ---------------------------------------------------------------------------
// B^T GEMM: C[m][n] = sum_k A[m][k] * W[n][k].  m97-style 128x128 tile, BK=32.
// ---------------------------------------------------------------------------
template <bool F32OUT>
__global__ __launch_bounds__(256) void gemm_bt(
    const u16* __restrict__ A, int lda,
    const u16* __restrict__ W0, const u16* __restrict__ W1, const u16* __restrict__ W2,
    int n1, int n2, void* __restrict__ Cv, int ldc, int K)
{
    __shared__ __align__(16) u16 As[128 * 32];
    __shared__ __align__(16) u16 Bs[128 * 32];
    const int t  = threadIdx.x;
    const int m0 = blockIdx.x * 128, n0 = blockIdx.y * 128;

    const u16* W; int nw;
    if (n0 < n1)      { W = W0; nw = n0; }
    else if (n0 < n2) { W = W1; nw = n0 - n1; }
    else              { W = W2; nw = n0 - n2; }

    const int lrow = t >> 2, lcol = (t & 3) * 8;
    const u16* gA = A + (size_t)(m0 + lrow) * lda + lcol;
    const u16* gB = W + (size_t)(nw + lrow) * K + lcol;

    const int wid = t >> 6, lane = t & 63;
    const int wm = (wid >> 1) * 64, wn = (wid & 1) * 64;
    const int l15 = lane & 15, quad = lane >> 4;

    v4f acc[4][4] = {};

    for (int k0 = 0; k0 < K; k0 += 32) {
        gl_lds16(gA + k0,                      As + t * 8);
        gl_lds16(gA + k0 + (size_t)64 * lda,   As + 2048 + t * 8);
        gl_lds16(gB + k0,                      Bs + t * 8);
        gl_lds16(gB + k0 + (size_t)64 * K,     Bs + 2048 + t * 8);
        __syncthreads();
        v8bf af[4], bfr[4];
#pragma unroll
        for (int i = 0; i < 4; i++) af[i]  = *(const v8bf_a*)(As + (wm + i * 16 + l15) * 32 + quad * 8);
#pragma unroll
        for (int j = 0; j < 4; j++) bfr[j] = *(const v8bf_a*)(Bs + (wn + j * 16 + l15) * 32 + quad * 8);
#pragma unroll
        for (int i = 0; i < 4; i++)
#pragma unroll
            for (int j = 0; j < 4; j++)
                acc[i][j] = __builtin_amdgcn_mfma_f32_16x16x32_bf16(af[i], bfr[j], acc[i][j], 0, 0, 0);
        __syncthreads();
    }

#pragma unroll
    for (int i = 0; i < 4; i++)
#pragma unroll
        for (int j = 0; j < 4; j++)
#pragma unroll
            for (int r = 0; r < 4; r++) {
                const int row = m0 + wm + i * 16 + quad * 4 + r;
                const int col = n0 + wn + j * 16 + l15;
                if (F32OUT) ((float*)Cv)[(size_t)row * ldc + col] = acc[i][j][r];
                else        ((u16*)Cv)[(size_t)row * ldc + col]   = f2bf(acc[i][j][r]);
            }
}

// ---------------------------------------------------------------------------
// RMSNorm + RoPE on q (16 heads) and k (8 heads), IN-PLACE on qkv.
// ---------------------------------------------------------------------------
__global__ __launch_bounds__(256) void normrope(
    u16* __restrict__ qkv, const u16* __restrict__ qw, const u16* __restrict__ kw)
{
    const int tok = blockIdx.x;
    const int s = tok & 2047;
    const int wid = threadIdx.x >> 6, lane = threadIdx.x & 63;
    const int d  = lane * 2;
    const int dm = d & 63;
    const float kln = 9.210340371976184f / 64.f;
    const float inv0 = expf(-(float)dm * kln);
    const float inv1 = expf(-(float)(dm + 1) * kln);
    float sn0, cs0, sn1, cs1;
    __sincosf((float)s * inv0, &sn0, &cs0);
    __sincosf((float)s * inv1, &sn1, &cs1);

    for (int task = wid; task < 24; task += 4) {
        const bool isq = task < 16;
        const int  hh  = isq ? task : task - 16;
        u16* p = qkv + (size_t)tok * 4096 + (isq ? hh * 128 : 2048 + hh * 128) + d;
        const float x0 = bf2f(p[0]), x1 = bf2f(p[1]);
        float ss = x0 * x0 + x1 * x1;
#pragma unroll
        for (int off = 32; off; off >>= 1) ss += __shfl_xor(ss, off);
        const float rr = rsqrtf(ss * (1.f / 128.f) + 1e-6f);
        const u16* wp = (isq ? qw : kw) + d;
        const float xn0 = x0 * rr * (1.f + bf2f(wp[0]));
        const float xn1 = x1 * rr * (1.f + bf2f(wp[1]));
        const float pp0 = __shfl_xor(xn0, 32);
        const float pp1 = __shfl_xor(xn1, 32);
        float o0, o1;
        if (lane < 32) { o0 = xn0 * cs0 - pp0 * sn0; o1 = xn1 * cs1 - pp1 * sn1; }
        else           { o0 = xn0 * cs0 + pp0 * sn0; o1 = xn1 * cs1 + pp1 * sn1; }
        p[0] = f2bf(o0); p[1] = f2bf(o1);
    }
}

// ---------------------------------------------------------------------------
// V transpose: qkv v-cols [tok][3072 + c]  ->  v_t[b*1024 + c][s]
// ---------------------------------------------------------------------------
__global__ __launch_bounds__(256) void vtrans(
    const u16* __restrict__ qkv, u16* __restrict__ v_t)
{
    __shared__ __align__(16) u16 tile[64][80];
    const int b = blockIdx.x, st = blockIdx.y * 64, ct = blockIdx.z * 64;
    const int t = threadIdx.x;
    {
        const int sl = t >> 2, cq = (t & 3) * 16;
        const u16* src = qkv + ((size_t)(b * 2048 + st + sl)) * 4096 + 3072 + ct + cq;
        *(v8u16_a*)&tile[sl][cq]     = *(const v8u16_a*)src;
        *(v8u16_a*)&tile[sl][cq + 8] = *(const v8u16_a*)(src + 8);
    }
    __syncthreads();
    {
        const int dl = t >> 2, sq = (t & 3) * 16;
        v8u16 o0, o1;
#pragma unroll
        for (int i = 0; i < 8; i++) { o0[i] = tile[sq + i][dl]; o1[i] = tile[sq + 8 + i][dl]; }
        u16* dst = v_t + ((size_t)(b * 1024 + ct + dl)) * 2048 + st + sq;
        *(v8u16_a*)dst       = o0;
        *(v8u16_a*)(dst + 8) = o1;
    }
}

// ---------------------------------------------------------------------------
// Flash attention, sliding window 1024, GQA groups=2. Block = 64 queries x 1
// head (4 waves x 16 q). K tiles (32x128) staged via global_load_lds
// (XOR-swizzled 16B chunks), double-buffered, one __syncthreads per tile.
// Round-N changes:
//  * defer-max (T13, THR = 8/scale in raw-score units): skip O-rescale +
//    max-update while tile max stays within THR of running max.
//  * scale folded into exp (track raw max; p = exp((s - m)*scale)).
//  * P pack via HW v_cvt_pk_bf16_f32 (T12 recipe), replaces 24 bit-ops.
//  * P-tile stride 48 -> 72 u16 (144B, 16B-aligned): 4-way -> 2-way banks.
//  * heavy q-tiles launch first (flip blockIdx.y) to shrink straggler tail.
//  * waves skip fully-masked K-tiles (staging + barrier participation kept).
// ---------------------------------------------------------------------------
__global__ __launch_bounds__(256) void attn_fa(
    const u16* __restrict__ qkv,   // [tok][4096]
    const u16* __restrict__ v_t,   // [b*1024 + kvh*128+d][2048]
    u16* __restrict__ attn)        // [tok][h*128+d]
{
    __shared__ __align__(16) u16 Ks[2][32 * 128];
    __shared__ __align__(16) u16 p_lds[4][16 * 72];
    const int bh = blockIdx.x;
    const int b = bh >> 4, h = bh & 15, kvh = h >> 1;
    const int t = threadIdx.x;
    const int wid = t >> 6, lane = t & 63;
    const int l15 = lane & 15, quad = lane >> 4;
    const int qb0 = ((int)gridDim.y - 1 - (int)blockIdx.y) * 64;  // heavy first
    const int qw0 = qb0 + wid * 16;
    const int q   = qw0 + l15;

    const u16* Qb = qkv + ((size_t)(b * 2048 + q)) * 4096 + h * 128 + quad * 8;
    v8bf qf[4];
#pragma unroll
    for (int kc = 0; kc < 4; kc++) qf[kc] = *(const v8bf_a*)(Qb + kc * 32);

    const u16* Kb = qkv + (size_t)b * 2048 * 4096 + 2048 + kvh * 128;
    const u16* Vb = v_t + (size_t)(b * 1024 + kvh * 128) * 2048;

    // block-uniform K range
    int ks = qb0 - 1023; if (ks < 0) ks = 0;
    const int kstart = ks & ~31, kend = qb0 + 63;

    // staging map: thread t covers (row, chunk16) = (t>>4, t&15) and (+16, same)
    const int sr0 = t >> 4, sc = t & 15, sr1 = sr0 + 16;
    const int so0 = (sc ^ (sr0 & 7)) * 8;   // swizzled source col (u16)
    const int so1 = (sc ^ (sr1 & 7)) * 8;

    gl_lds16(Kb + (size_t)(kstart + sr0) * 4096 + so0, &Ks[0][(size_t)t * 8]);
    gl_lds16(Kb + (size_t)(kstart + sr1) * 4096 + so1, &Ks[0][(size_t)(256 + t) * 8]);

    v4f o[8] = {};             // O^T: d = nt*16 + quad*4 + r, query = l15
    float m_run = -INFINITY;   // running max of RAW scores
    float msafe = 0.f;         // -inf-safe copy used for exp
    float l_i = 0.f;
    const float kSc = 0.08838834764831845f;   // 1/sqrt(128)
    const float THR = 90.50966799187808f;     // 8 / kSc
    u16* P = &p_lds[wid][0];
    const int swz = l15 & 7;

    int buf = 0;
    for (int kt = kstart; kt <= kend; kt += 32, buf ^= 1) {
        __syncthreads();   // staging of `buf` complete; prior reads of buf^1 done
        if (kt + 32 <= kend) {
            gl_lds16(Kb + (size_t)(kt + 32 + sr0) * 4096 + so0, &Ks[buf ^ 1][(size_t)t * 8]);
            gl_lds16(Kb + (size_t)(kt + 32 + sr1) * 4096 + so1, &Ks[buf ^ 1][(size_t)(256 + t) * 8]);
        }
        // wave-uniform: skip tiles fully masked for this wave's 16 queries
        if (kt > qw0 + 15 || kt + 31 <= qw0 - 1024) continue;

        // V fragments: issue early, overlap with QK + softmax
        v8bf vf[8];
        const u16* Vr = Vb + (size_t)l15 * 2048 + kt + quad * 8;
#pragma unroll
        for (int nt = 0; nt < 8; nt++) vf[nt] = *(const v8bf_a*)(Vr + (size_t)nt * 16 * 2048);

        // QK from swizzled LDS: rows l15 / l15+16, d-chunk (kc*4+quad)^swz
        v4f s0 = {}, s1 = {};
        const u16* K0 = &Ks[buf][(size_t)l15 * 128];
        const u16* K1 = K0 + 16 * 128;
#pragma unroll
        for (int kc = 0; kc < 4; kc++) {
            const int cs = ((kc * 4 + quad) ^ swz) * 8;
            s0 = __builtin_amdgcn_mfma_f32_16x16x32_bf16(*(const v8bf_a*)(K0 + cs), qf[kc], s0, 0, 0, 0);
            s1 = __builtin_amdgcn_mfma_f32_16x16x32_bf16(*(const v8bf_a*)(K1 + cs), qf[kc], s1, 0, 0, 0);
        }

        // mask (raw scores); this lane's keys: kt+quad*4+r (s0), +16 (s1)
        float p[8];
        float mx = -INFINITY;
#pragma unroll
        for (int r = 0; r < 4; r++) {
            const int kk0 = kt + quad * 4 + r, kk1 = kk0 + 16;
            const float v0 = (kk0 <= q && kk0 > q - 1024) ? s0[r] : -INFINITY;
            const float v1 = (kk1 <= q && kk1 > q - 1024) ? s1[r] : -INFINITY;
            p[r] = v0; p[r + 4] = v1;
            mx = fmaxf(mx, fmaxf(v0, v1));
        }
        mx = fmaxf(mx, __shfl_xor(mx, 16));
        mx = fmaxf(mx, __shfl_xor(mx, 32));

        // defer-max: only rescale when some query's max grew past THR
        if (!__all(mx <= m_run + THR)) {
            const float mnew  = fmaxf(m_run, mx);
            const float msn   = (mnew == -INFINITY) ? 0.f : mnew;
            const float alpha = __expf((m_run - msn) * kSc);  // -inf -> 0
#pragma unroll
            for (int nt = 0; nt < 8; nt++)
#pragma unroll
                for (int r = 0; r < 4; r++) o[nt][r] *= alpha;
            l_i *= alpha;
            m_run = mnew; msafe = msn;
        }

        const float mb = msafe * kSc;
        float ps = 0.f;
#pragma unroll
        for (int j = 0; j < 8; j++) {
            p[j] = __expf(__builtin_fmaf(p[j], kSc, -mb));  // masked -inf -> 0
            ps += p[j];
        }

        // P^T -> per-wave LDS via HW packed cvt: row = query l15 (stride 72)
        union { v4u16 v; uint32_t d[2]; } u0, u1;
        asm("v_cvt_pk_bf16_f32 %0, %1, %2" : "=v"(u0.d[0]) : "v"(p[0]), "v"(p[1]));
        asm("v_cvt_pk_bf16_f32 %0, %1, %2" : "=v"(u0.d[1]) : "v"(p[2]), "v"(p[3]));
        asm("v_cvt_pk_bf16_f32 %0, %1, %2" : "=v"(u1.d[0]) : "v"(p[4]), "v"(p[5]));
        asm("v_cvt_pk_bf16_f32 %0, %1, %2" : "=v"(u1.d[1]) : "v"(p[6]), "v"(p[7]));
        *(v4u16_a*)(P + l15 * 72 + quad * 4)      = u0.v;
        *(v4u16_a*)(P + l15 * 72 + 16 + quad * 4) = u1.v;

        // row-sum reduce + l update between write and wait (covers ds latency)
        ps += __shfl_xor(ps, 16);
        ps += __shfl_xor(ps, 32);
        l_i += ps;

        asm volatile("s_waitcnt lgkmcnt(0)" ::: "memory");
        const v8bf pf = *(const v8bf_a*)(P + l15 * 72 + quad * 8);  // B-frag of P^T
#pragma unroll
        for (int nt = 0; nt < 8; nt++)
            o[nt] = __builtin_amdgcn_mfma_f32_16x16x32_bf16(vf[nt], pf, o[nt], 0, 0, 0);
    }

    const float inv = 1.0f / l_i;
    u16* orow = attn + ((size_t)(b * 2048 + q)) * 2048 + h * 128 + quad * 4;
#pragma unroll
    for (int nt = 0; nt < 8; nt++) {
        v4u16 ov;
#pragma unroll
        for (int r = 0; r < 4; r++) ov[r] = f2bf(o[nt][r] * inv);
        *(v4u16_a*)(orow + nt * 16) = ov;
    }
}

// ---------------------------------------------------------------------------
extern "C" void kernel_launch(void* const* d_in, const int* in_sizes, int n_in,
                              void* d_out, int out_size, void* d_ws, size_t ws_size,
                              hipStream_t stream)
{
    // workspace layout (u16 elements)
    u16* qkv  = (u16*)d_ws;                            // [4096][4096]
    u16* v_t  = qkv  + (size_t)16777216;               // [2048][2048]
    u16* xa   = v_t  + (size_t)4194304;                // x_bf16, later attn
    u16* wbf  = xa   + (size_t)8388608;                // wq|wk|wv, later wo
    u16* nwq  = wbf  + (size_t)8388608;                // 128
    u16* nwk  = nwq  + 128;                            // 128

    // 0) materialize bf16 copies of fp32 inputs
    convert_bf16<<<4096, 256, 0, stream>>>((const float*)d_in[0], xa,            8388608); // x
    convert_bf16<<<2048, 256, 0, stream>>>((const float*)d_in[1], wbf,           4194304); // wq
    convert_bf16<<<1024, 256, 0, stream>>>((const float*)d_in[2], wbf + 4194304, 2097152); // wk
    convert_bf16<<<1024, 256, 0, stream>>>((const float*)d_in[3], wbf + 6291456, 2097152); // wv
    convert_bf16<<<1,    256, 0, stream>>>((const float*)d_in[5], nwq,           128);     // q_norm
    convert_bf16<<<1,    256, 0, stream>>>((const float*)d_in[6], nwk,           128);     // k_norm
    // 1) fused QKV projection
    gemm_bt<false><<<dim3(32, 32), 256, 0, stream>>>(xa, 2048, wbf, wbf + 4194304, wbf + 6291456,
                                                     2048, 3072, qkv, 4096, 2048);
    // 2) wo -> bf16, overwriting the now-dead wq slot
    convert_bf16<<<2048, 256, 0, stream>>>((const float*)d_in[4], wbf, 4194304);
    // 3) RMSNorm + RoPE for q,k (in-place)
    normrope<<<dim3(4096), 256, 0, stream>>>(qkv, nwq, nwk);
    // 4) V transpose for PV A-operand
    vtrans<<<dim3(2, 32, 16), 256, 0, stream>>>(qkv, v_t);
    // 5) sliding-window flash attention (attn overwrites dead x_bf16)
    attn_fa<<<dim3(32, 32), 256, 0, stream>>>(qkv, v_t, xa);
    // 6) output projection -> d_out as FP32 (reference output dtype)
    gemm_bt<true><<<dim3(32, 16), 256, 0, stream>>>(xa, 2048, wbf, wbf, wbf,
                                                    2048, 4096, d_out, 2048, 2048);
}

// Round 2
// 396.245 us; speedup vs baseline: 1.0953x; 1.0429x over previous
//
#include <hip/hip_runtime.h>
#include <stdint.h>
#include <math.h>

typedef unsigned short u16;
typedef __attribute__((ext_vector_type(8))) __bf16 v8bf;
typedef v8bf __attribute__((may_alias)) v8bf_a;
typedef __attribute__((ext_vector_type(4))) float v4f;
typedef __attribute__((ext_vector_type(4))) u16 v4u16;
typedef v4u16 __attribute__((may_alias)) v4u16_a;
typedef __attribute__((ext_vector_type(8))) u16 v8u16;
typedef v8u16 __attribute__((may_alias)) v8u16_a;

__device__ __forceinline__ float bf2f(u16 u) {
    union { uint32_t i; float f; } c; c.i = ((uint32_t)u) << 16; return c.f;
}
__device__ __forceinline__ u16 f2bf(float f) {
    union { float f; uint32_t i; } c; c.f = f;
    return (u16)((c.i + 0x7FFFu + ((c.i >> 16) & 1u)) >> 16);
}
__device__ __forceinline__ void gl_lds16(const u16* g, u16* l) {
    __builtin_amdgcn_global_load_lds(
        (const __attribute__((address_space(1))) void*)g,
        (__attribute__((address_space(3))) void*)l, 16, 0, 0);
}

// ---------------------------------------------------------------------------
// fp32 -> bf16 conversion (inputs are fp32: proven by round-2/3 NaN bisect).
// ---------------------------------------------------------------------------
__global__ __launch_bounds__(256) void convert_bf16(
    const float* __restrict__ src, u16* __restrict__ dst, int n)
{
    const int stride = gridDim.x * blockDim.x;
    for (int i = blockIdx.x * blockDim.x + threadIdx.x; i * 8 < n; i += stride) {
        const int base = i * 8;
        v8u16 o;
#pragma unroll
        for (int j = 0; j < 8; j++) o[j] = f2bf(src[base + j]);
        *(v8u16_a*)(dst + base) = o;
    }
}

// ---------------------------------------------------------------------------
// B^T GEMM, pipelined: C[m][n] = sum_k A[m][k] * W[n][k].
// BM=BN=256, BK=32, 512 threads = 8 waves (2M x 4N), wave-tile 128x64.
// 3 LDS buffers (96 KiB), prefetch distance 2, counted s_waitcnt vmcnt(4)
// (tile t drained while tile t+1's 4 loads stay in flight), raw s_barrier
// (no compiler vmcnt(0) drain).  LDS layout is FRAGMENT-MAJOR: [16-row x 32-k]
// blocks stored k-chunk-major so every MFMA fragment read is base + lane*16
// -> linear, zero bank conflicts; gl_lds dest stays linear (per-lane freedom
// is on the GLOBAL source side only).
//   staging chunk c (=j*512+t): global A[(c>>6)*16 + (c&15)][((c>>4)&3)*8 + k0]
//                               -> LDS byte c*16.
//   read: frag block (wr8+i) / (wc4+j): base + block*1024B + lane*16B.
// ---------------------------------------------------------------------------
template <bool F32OUT>
__global__ __launch_bounds__(512) void gemm_p3(
    const u16* __restrict__ A, int lda,
    const u16* __restrict__ W0, const u16* __restrict__ W1, const u16* __restrict__ W2,
    int n1, int n2, void* __restrict__ Cv, int ldc, int K)
{
    __shared__ __align__(16) u16 lds[3][16384];   // per buf: A 8192 u16, B 8192 u16
    const int t  = threadIdx.x;
    const int m0 = blockIdx.x * 256, n0 = blockIdx.y * 256;

    const u16* W; int nw;
    if (n0 < n1)      { W = W0; nw = n0; }
    else if (n0 < n2) { W = W1; nw = n0 - n1; }
    else              { W = W2; nw = n0 - n2; }

    // staging sources for chunks c0 = t, c1 = 512 + t
    const int c0 = t, c1 = 512 + t;
    const int ra0 = ((c0 >> 6) << 4) + (c0 & 15), ca0 = ((c0 >> 4) & 3) << 3;
    const int ra1 = ((c1 >> 6) << 4) + (c1 & 15), ca1 = ((c1 >> 4) & 3) << 3;
    const u16* sa0 = A + (size_t)(m0 + ra0) * lda + ca0;
    const u16* sa1 = A + (size_t)(m0 + ra1) * lda + ca1;
    const u16* sb0 = W + (size_t)(nw + ra0) * K   + ca0;
    const u16* sb1 = W + (size_t)(nw + ra1) * K   + ca1;

#define STAGE_P3(koff, dst)                                  \
    do {                                                     \
        gl_lds16(sa0 + (koff), (dst) + c0 * 8);              \
        gl_lds16(sa1 + (koff), (dst) + c1 * 8);              \
        gl_lds16(sb0 + (koff), (dst) + 8192 + c0 * 8);       \
        gl_lds16(sb1 + (koff), (dst) + 8192 + c1 * 8);       \
    } while (0)

    const int NT = K >> 5;             // 32-wide K tiles
    STAGE_P3(0,  lds[0]);              // prologue: tiles 0,1 in flight (8 loads)
    STAGE_P3(32, lds[1]);

    const int wid = t >> 6, lane = t & 63;
    const int l15 = lane & 15, quad = lane >> 4;
    const int wr8 = (wid >> 2) << 3;   // A frag-block base (x8)
    const int wc4 = (wid & 3) << 2;    // B frag-block base (x4)
    const int lofs = lane << 3;        // lane*8 u16 = lane*16 B

    v4f acc[8][4] = {};
    int bb = 0;
    for (int kt = 0; kt < NT; ++kt) {
        // tile kt's 4 loads are the oldest; tile kt+1's 4 stay in flight
        if (kt < NT - 1) asm volatile("s_waitcnt vmcnt(4)" ::: "memory");
        else             asm volatile("s_waitcnt vmcnt(0)" ::: "memory");
        __builtin_amdgcn_s_barrier();   // all waves' tile-kt data visible;
                                        // all waves done reading buf (bb+2)%3
        if (kt + 2 < NT) {
            int nb = bb + 2; if (nb >= 3) nb -= 3;
            STAGE_P3((kt + 2) * 32, lds[nb]);
        }
        const u16* Ab = lds[bb];
        const u16* Bb = Ab + 8192;
        v8bf af[8], bv[4];
#pragma unroll
        for (int i = 0; i < 8; i++) af[i] = *(const v8bf_a*)(Ab + ((wr8 + i) << 9) + lofs);
#pragma unroll
        for (int j = 0; j < 4; j++) bv[j] = *(const v8bf_a*)(Bb + ((wc4 + j) << 9) + lofs);
        __builtin_amdgcn_s_setprio(1);
#pragma unroll
        for (int i = 0; i < 8; i++)
#pragma unroll
            for (int j = 0; j < 4; j++)
                acc[i][j] = __builtin_amdgcn_mfma_f32_16x16x32_bf16(af[i], bv[j], acc[i][j], 0, 0, 0);
        __builtin_amdgcn_s_setprio(0);
        bb = (bb == 2) ? 0 : bb + 1;
    }
#undef STAGE_P3

#pragma unroll
    for (int i = 0; i < 8; i++)
#pragma unroll
        for (int j = 0; j < 4; j++)
#pragma unroll
            for (int r = 0; r < 4; r++) {
                const int row = m0 + (wr8 + i) * 16 + quad * 4 + r;
                const int col = n0 + (wc4 + j) * 16 + l15;
                if (F32OUT) ((float*)Cv)[(size_t)row * ldc + col] = acc[i][j][r];
                else        ((u16*)Cv)[(size_t)row * ldc + col]   = f2bf(acc[i][j][r]);
            }
}

// ---------------------------------------------------------------------------
// RMSNorm + RoPE on q (16 heads) and k (8 heads), IN-PLACE on qkv.
// ---------------------------------------------------------------------------
__global__ __launch_bounds__(256) void normrope(
    u16* __restrict__ qkv, const u16* __restrict__ qw, const u16* __restrict__ kw)
{
    const int tok = blockIdx.x;
    const int s = tok & 2047;
    const int wid = threadIdx.x >> 6, lane = threadIdx.x & 63;
    const int d  = lane * 2;
    const int dm = d & 63;
    const float kln = 9.210340371976184f / 64.f;
    const float inv0 = expf(-(float)dm * kln);
    const float inv1 = expf(-(float)(dm + 1) * kln);
    float sn0, cs0, sn1, cs1;
    __sincosf((float)s * inv0, &sn0, &cs0);
    __sincosf((float)s * inv1, &sn1, &cs1);

    for (int task = wid; task < 24; task += 4) {
        const bool isq = task < 16;
        const int  hh  = isq ? task : task - 16;
        u16* p = qkv + (size_t)tok * 4096 + (isq ? hh * 128 : 2048 + hh * 128) + d;
        const float x0 = bf2f(p[0]), x1 = bf2f(p[1]);
        float ss = x0 * x0 + x1 * x1;
#pragma unroll
        for (int off = 32; off; off >>= 1) ss += __shfl_xor(ss, off);
        const float rr = rsqrtf(ss * (1.f / 128.f) + 1e-6f);
        const u16* wp = (isq ? qw : kw) + d;
        const float xn0 = x0 * rr * (1.f + bf2f(wp[0]));
        const float xn1 = x1 * rr * (1.f + bf2f(wp[1]));
        const float pp0 = __shfl_xor(xn0, 32);
        const float pp1 = __shfl_xor(xn1, 32);
        float o0, o1;
        if (lane < 32) { o0 = xn0 * cs0 - pp0 * sn0; o1 = xn1 * cs1 - pp1 * sn1; }
        else           { o0 = xn0 * cs0 + pp0 * sn0; o1 = xn1 * cs1 + pp1 * sn1; }
        p[0] = f2bf(o0); p[1] = f2bf(o1);
    }
}

// ---------------------------------------------------------------------------
// V transpose: qkv v-cols [tok][3072 + c]  ->  v_t[b*1024 + c][s]
// ---------------------------------------------------------------------------
__global__ __launch_bounds__(256) void vtrans(
    const u16* __restrict__ qkv, u16* __restrict__ v_t)
{
    __shared__ __align__(16) u16 tile[64][80];
    const int b = blockIdx.x, st = blockIdx.y * 64, ct = blockIdx.z * 64;
    const int t = threadIdx.x;
    {
        const int sl = t >> 2, cq = (t & 3) * 16;
        const u16* src = qkv + ((size_t)(b * 2048 + st + sl)) * 4096 + 3072 + ct + cq;
        *(v8u16_a*)&tile[sl][cq]     = *(const v8u16_a*)src;
        *(v8u16_a*)&tile[sl][cq + 8] = *(const v8u16_a*)(src + 8);
    }
    __syncthreads();
    {
        const int dl = t >> 2, sq = (t & 3) * 16;
        v8u16 o0, o1;
#pragma unroll
        for (int i = 0; i < 8; i++) { o0[i] = tile[sq + i][dl]; o1[i] = tile[sq + 8 + i][dl]; }
        u16* dst = v_t + ((size_t)(b * 1024 + ct + dl)) * 2048 + st + sq;
        *(v8u16_a*)dst       = o0;
        *(v8u16_a*)(dst + 8) = o1;
    }
}

// ---------------------------------------------------------------------------
// Flash attention, sliding window 1024, GQA groups=2. Block = 64 queries x 1
// head (4 waves x 16 q). K tiles (32x128) staged via global_load_lds
// (XOR-swizzled 16B chunks), double-buffered, one __syncthreads per tile.
// defer-max (T13), scale folded into exp, v_cvt_pk_bf16_f32 P-pack, P stride
// 72, heavy q-tiles first, fully-masked-tile skip.
// ---------------------------------------------------------------------------
__global__ __launch_bounds__(256) void attn_fa(
    const u16* __restrict__ qkv,   // [tok][4096]
    const u16* __restrict__ v_t,   // [b*1024 + kvh*128+d][2048]
    u16* __restrict__ attn)        // [tok][h*128+d]
{
    __shared__ __align__(16) u16 Ks[2][32 * 128];
    __shared__ __align__(16) u16 p_lds[4][16 * 72];
    const int bh = blockIdx.x;
    const int b = bh >> 4, h = bh & 15, kvh = h >> 1;
    const int t = threadIdx.x;
    const int wid = t >> 6, lane = t & 63;
    const int l15 = lane & 15, quad = lane >> 4;
    const int qb0 = ((int)gridDim.y - 1 - (int)blockIdx.y) * 64;  // heavy first
    const int qw0 = qb0 + wid * 16;
    const int q   = qw0 + l15;

    const u16* Qb = qkv + ((size_t)(b * 2048 + q)) * 4096 + h * 128 + quad * 8;
    v8bf qf[4];
#pragma unroll
    for (int kc = 0; kc < 4; kc++) qf[kc] = *(const v8bf_a*)(Qb + kc * 32);

    const u16* Kb = qkv + (size_t)b * 2048 * 4096 + 2048 + kvh * 128;
    const u16* Vb = v_t + (size_t)(b * 1024 + kvh * 128) * 2048;

    // block-uniform K range
    int ks = qb0 - 1023; if (ks < 0) ks = 0;
    const int kstart = ks & ~31, kend = qb0 + 63;

    // staging map: thread t covers (row, chunk16) = (t>>4, t&15) and (+16, same)
    const int sr0 = t >> 4, sc = t & 15, sr1 = sr0 + 16;
    const int so0 = (sc ^ (sr0 & 7)) * 8;   // swizzled source col (u16)
    const int so1 = (sc ^ (sr1 & 7)) * 8;

    gl_lds16(Kb + (size_t)(kstart + sr0) * 4096 + so0, &Ks[0][(size_t)t * 8]);
    gl_lds16(Kb + (size_t)(kstart + sr1) * 4096 + so1, &Ks[0][(size_t)(256 + t) * 8]);

    v4f o[8] = {};             // O^T: d = nt*16 + quad*4 + r, query = l15
    float m_run = -INFINITY;   // running max of RAW scores
    float msafe = 0.f;         // -inf-safe copy used for exp
    float l_i = 0.f;
    const float kSc = 0.08838834764831845f;   // 1/sqrt(128)
    const float THR = 90.50966799187808f;     // 8 / kSc
    u16* P = &p_lds[wid][0];
    const int swz = l15 & 7;

    int buf = 0;
    for (int kt = kstart; kt <= kend; kt += 32, buf ^= 1) {
        __syncthreads();   // staging of `buf` complete; prior reads of buf^1 done
        if (kt + 32 <= kend) {
            gl_lds16(Kb + (size_t)(kt + 32 + sr0) * 4096 + so0, &Ks[buf ^ 1][(size_t)t * 8]);
            gl_lds16(Kb + (size_t)(kt + 32 + sr1) * 4096 + so1, &Ks[buf ^ 1][(size_t)(256 + t) * 8]);
        }
        // wave-uniform: skip tiles fully masked for this wave's 16 queries
        if (kt > qw0 + 15 || kt + 31 <= qw0 - 1024) continue;

        // V fragments: issue early, overlap with QK + softmax
        v8bf vf[8];
        const u16* Vr = Vb + (size_t)l15 * 2048 + kt + quad * 8;
#pragma unroll
        for (int nt = 0; nt < 8; nt++) vf[nt] = *(const v8bf_a*)(Vr + (size_t)nt * 16 * 2048);

        // QK from swizzled LDS: rows l15 / l15+16, d-chunk (kc*4+quad)^swz
        v4f s0 = {}, s1 = {};
        const u16* K0 = &Ks[buf][(size_t)l15 * 128];
        const u16* K1 = K0 + 16 * 128;
#pragma unroll
        for (int kc = 0; kc < 4; kc++) {
            const int cs = ((kc * 4 + quad) ^ swz) * 8;
            s0 = __builtin_amdgcn_mfma_f32_16x16x32_bf16(*(const v8bf_a*)(K0 + cs), qf[kc], s0, 0, 0, 0);
            s1 = __builtin_amdgcn_mfma_f32_16x16x32_bf16(*(const v8bf_a*)(K1 + cs), qf[kc], s1, 0, 0, 0);
        }

        // mask (raw scores); this lane's keys: kt+quad*4+r (s0), +16 (s1)
        float p[8];
        float mx = -INFINITY;
#pragma unroll
        for (int r = 0; r < 4; r++) {
            const int kk0 = kt + quad * 4 + r, kk1 = kk0 + 16;
            const float v0 = (kk0 <= q && kk0 > q - 1024) ? s0[r] : -INFINITY;
            const float v1 = (kk1 <= q && kk1 > q - 1024) ? s1[r] : -INFINITY;
            p[r] = v0; p[r + 4] = v1;
            mx = fmaxf(mx, fmaxf(v0, v1));
        }
        mx = fmaxf(mx, __shfl_xor(mx, 16));
        mx = fmaxf(mx, __shfl_xor(mx, 32));

        // defer-max: only rescale when some query's max grew past THR
        if (!__all(mx <= m_run + THR)) {
            const float mnew  = fmaxf(m_run, mx);
            const float msn   = (mnew == -INFINITY) ? 0.f : mnew;
            const float alpha = __expf((m_run - msn) * kSc);  // -inf -> 0
#pragma unroll
            for (int nt = 0; nt < 8; nt++)
#pragma unroll
                for (int r = 0; r < 4; r++) o[nt][r] *= alpha;
            l_i *= alpha;
            m_run = mnew; msafe = msn;
        }

        const float mb = msafe * kSc;
        float ps = 0.f;
#pragma unroll
        for (int j = 0; j < 8; j++) {
            p[j] = __expf(__builtin_fmaf(p[j], kSc, -mb));  // masked -inf -> 0
            ps += p[j];
        }

        // P^T -> per-wave LDS via HW packed cvt: row = query l15 (stride 72)
        union { v4u16 v; uint32_t d[2]; } u0, u1;
        asm("v_cvt_pk_bf16_f32 %0, %1, %2" : "=v"(u0.d[0]) : "v"(p[0]), "v"(p[1]));
        asm("v_cvt_pk_bf16_f32 %0, %1, %2" : "=v"(u0.d[1]) : "v"(p[2]), "v"(p[3]));
        asm("v_cvt_pk_bf16_f32 %0, %1, %2" : "=v"(u1.d[0]) : "v"(p[4]), "v"(p[5]));
        asm("v_cvt_pk_bf16_f32 %0, %1, %2" : "=v"(u1.d[1]) : "v"(p[6]), "v"(p[7]));
        *(v4u16_a*)(P + l15 * 72 + quad * 4)      = u0.v;
        *(v4u16_a*)(P + l15 * 72 + 16 + quad * 4) = u1.v;

        // row-sum reduce + l update between write and wait (covers ds latency)
        ps += __shfl_xor(ps, 16);
        ps += __shfl_xor(ps, 32);
        l_i += ps;

        asm volatile("s_waitcnt lgkmcnt(0)" ::: "memory");
        const v8bf pf = *(const v8bf_a*)(P + l15 * 72 + quad * 8);  // B-frag of P^T
#pragma unroll
        for (int nt = 0; nt < 8; nt++)
            o[nt] = __builtin_amdgcn_mfma_f32_16x16x32_bf16(vf[nt], pf, o[nt], 0, 0, 0);
    }

    const float inv = 1.0f / l_i;
    u16* orow = attn + ((size_t)(b * 2048 + q)) * 2048 + h * 128 + quad * 4;
#pragma unroll
    for (int nt = 0; nt < 8; nt++) {
        v4u16 ov;
#pragma unroll
        for (int r = 0; r < 4; r++) ov[r] = f2bf(o[nt][r] * inv);
        *(v4u16_a*)(orow + nt * 16) = ov;
    }
}

// ---------------------------------------------------------------------------
extern "C" void kernel_launch(void* const* d_in, const int* in_sizes, int n_in,
                              void* d_out, int out_size, void* d_ws, size_t ws_size,
                              hipStream_t stream)
{
    // workspace layout (u16 elements)
    u16* qkv  = (u16*)d_ws;                            // [4096][4096]
    u16* v_t  = qkv  + (size_t)16777216;               // [2048][2048]
    u16* xa   = v_t  + (size_t)4194304;                // x_bf16, later attn
    u16* wbf  = xa   + (size_t)8388608;                // wq|wk|wv, later wo
    u16* nwq  = wbf  + (size_t)8388608;                // 128
    u16* nwk  = nwq  + 128;                            // 128

    // 0) materialize bf16 copies of fp32 inputs
    convert_bf16<<<4096, 256, 0, stream>>>((const float*)d_in[0], xa,            8388608); // x
    convert_bf16<<<2048, 256, 0, stream>>>((const float*)d_in[1], wbf,           4194304); // wq
    convert_bf16<<<1024, 256, 0, stream>>>((const float*)d_in[2], wbf + 4194304, 2097152); // wk
    convert_bf16<<<1024, 256, 0, stream>>>((const float*)d_in[3], wbf + 6291456, 2097152); // wv
    convert_bf16<<<1,    256, 0, stream>>>((const float*)d_in[5], nwq,           128);     // q_norm
    convert_bf16<<<1,    256, 0, stream>>>((const float*)d_in[6], nwk,           128);     // k_norm
    // 1) fused QKV projection (pipelined 256x256 tiles)
    gemm_p3<false><<<dim3(16, 16), 512, 0, stream>>>(xa, 2048, wbf, wbf + 4194304, wbf + 6291456,
                                                     2048, 3072, qkv, 4096, 2048);
    // 2) wo -> bf16, overwriting the now-dead wq slot
    convert_bf16<<<2048, 256, 0, stream>>>((const float*)d_in[4], wbf, 4194304);
    // 3) RMSNorm + RoPE for q,k (in-place)
    normrope<<<dim3(4096), 256, 0, stream>>>(qkv, nwq, nwk);
    // 4) V transpose for PV A-operand
    vtrans<<<dim3(2, 32, 16), 256, 0, stream>>>(qkv, v_t);
    // 5) sliding-window flash attention (attn overwrites dead x_bf16)
    attn_fa<<<dim3(32, 32), 256, 0, stream>>>(qkv, v_t, xa);
    // 6) output projection -> d_out as FP32 (reference output dtype)
    gemm_p3<true><<<dim3(16, 8), 512, 0, stream>>>(xa, 2048, wbf, wbf, wbf,
                                                   4096, 4096, d_out, 2048, 2048);
}